// Round 9
// baseline (381.712 us; speedup 1.0000x reference)
//
#include <hip/hip_runtime.h>

#define HD 64       // HIDDEN_DIM
#define NE 512      // N_EMBEDS
#define HW 1024     // 32*32 spatial positions per batch image

// ---------------------------------------------------------------------------
// Prep (130 blocks x 256):
//  blk 0..127 : epT[c][k] = -2 * e[k][c]   (transposed, code-major rows)
//               -2 fold bit-exact (pow2 scale commutes with fp32 rounding).
//  blk 128/129: esq[k] = np.sum(e[k]*e[k]), numpy pairwise-8, no contraction.
//  Verified absmax==0.0 R1-R8.
// ---------------------------------------------------------------------------
__global__ __launch_bounds__(256) void vq_prep_kernel(const float* __restrict__ e,
                                                      float* __restrict__ epT,
                                                      float* __restrict__ esq) {
  const int blk = blockIdx.x;
  if (blk < 128) {
    const int t = blk * 256 + threadIdx.x;     // 0..32767
    const int c = t >> 9, k = t & 511;
    epT[t] = -2.0f * e[k * HD + c];
  } else {
    const int k = (blk - 128) * 256 + threadIdx.x;   // 0..511
    const float4* __restrict__ rowv = reinterpret_cast<const float4*>(e + k * HD);
    float row[HD];
    #pragma unroll
    for (int i = 0; i < 16; ++i) {
      const float4 v = rowv[i];
      row[4 * i + 0] = v.x; row[4 * i + 1] = v.y;
      row[4 * i + 2] = v.z; row[4 * i + 3] = v.w;
    }
    float result;
    {
      #pragma clang fp contract(off)
      float r[8];
      #pragma unroll
      for (int j = 0; j < 8; ++j) r[j] = row[j] * row[j];
      #pragma unroll
      for (int i = 8; i < HD; i += 8) {
        #pragma unroll
        for (int j = 0; j < 8; ++j) r[j] = r[j] + row[i + j] * row[i + j];
      }
      result = ((r[0] + r[1]) + (r[2] + r[3])) + ((r[4] + r[5]) + (r[6] + r[7]));
    }
    esq[k] = result;
  }
}

// ---------------------------------------------------------------------------
// Main R9: 2048 blocks x 256 (4 waves). Block = 32 positions x all 512 codes.
//
// R8 post-mortem: LDS pipe (shared per CU) binds at ~68 us -- 3 ds_read_b128
// per 32 FMAs. R9 doubles the register tile to 8 pos x 8 codes per lane:
// 4 ds_read_b128 per 64 FMAs (2x fewer LDS instrs per FMA). LDS model
// ~49 us/CU, VALU ~31 us -> expect main ~50-58 us.
//
// Geometry: wave w = code quarter wc. Lane: p=lane&3 -> positions
// posb=8p..8p+7; q=lane>>2 (0..15) -> codes kb=128wc+8q..+7. acc[8][8]
// persists over all c (c=0..63 ascending sequential fmaf chain per
// (pos,code) -- identical rounding to R3-R8 => absmax 0.0). Slot
// s=16wc+q covers codes [8s,8s+8); ascending-s combine == np.argmin
// first-index-wins. smin/sidx overlay es after final compute barrier.
// e staged through LDS in 8 c-chunks of 16 KB, software-pipelined with
// per-lane distinct float4 loads (VMEM stays negligible).
// ---------------------------------------------------------------------------
__global__ __launch_bounds__(256, 4) void vq_main_kernel(const float* __restrict__ x,
                                                         const float* __restrict__ epT,
                                                         const float* __restrict__ esq,
                                                         const float* __restrict__ e,
                                                         float* __restrict__ out) {
  __shared__ float xs[HD * 32];        // 8 KB   [c][pos]
  __shared__ float es[8 * NE];         // 16 KB  chunk [cc][k]; overlaid later
  __shared__ float xsq[32];
  __shared__ int   bcomb[32];

  float* smin = es;                    // [64 slots][32 pos] floats (8 KB)
  int*   sidx = (int*)(es + 64 * 32);  // [64 slots][32 pos] ints   (8 KB)

  const int t    = threadIdx.x;
  const int lane = t & 63;
  const int wc   = t >> 6;             // 0..3  wave = code quarter
  const int p    = lane & 3;           // pos-octet group
  const int q    = lane >> 2;          // 0..15 code slot
  const int posb = p * 8;              // lane's 8 positions
  const int kb   = wc * 128 + q * 8;   // lane's 8 codes

  const int blk = blockIdx.x;          // 2048
  const int b   = blk >> 5;
  const int s0  = (blk & 31) << 5;
  const size_t xbase = (size_t)b * (HD * HW) + s0;

  // ---- stage x into LDS [c][pos] (256 threads x 8 floats, coalesced)
  {
    const int pos = t & 31, cr = t >> 5;        // cr 0..7
    #pragma unroll
    for (int i = 0; i < 8; ++i) {
      const int c = cr + 8 * i;
      xs[c * 32 + pos] = x[xbase + (size_t)c * HW + pos];
    }
  }
  __syncthreads();

  // ---- xsq[pos]: numpy pairwise-8, no contraction (bit-exact)
  if (t < 32) {
    #pragma clang fp contract(off)
    float r[8];
    #pragma unroll
    for (int j = 0; j < 8; ++j) {
      const float v = xs[j * 32 + t];
      r[j] = v * v;
    }
    #pragma unroll
    for (int i = 8; i < HD; i += 8) {
      #pragma unroll
      for (int j = 0; j < 8; ++j) {
        const float v = xs[(i + j) * 32 + t];
        r[j] = r[j] + v * v;
      }
    }
    xsq[t] = ((r[0] + r[1]) + (r[2] + r[3])) + ((r[4] + r[5]) + (r[6] + r[7]));
  }

  // ---- chunked, software-pipelined e-staging + accumulate
  const float4* __restrict__ esrc = reinterpret_cast<const float4*>(epT); // 8192 float4
  float4 v0 = esrc[t];                 // chunk 0 prefetch (distinct 16B/lane)
  float4 v1 = esrc[t + 256];
  float4 v2 = esrc[t + 512];
  float4 v3 = esrc[t + 768];

  float acc[8][8];
  #pragma unroll
  for (int pi = 0; pi < 8; ++pi)
    #pragma unroll
    for (int j = 0; j < 8; ++j) acc[pi][j] = 0.f;

  #pragma unroll 1
  for (int ch = 0; ch < 8; ++ch) {
    __syncthreads();                   // previous chunk fully consumed
    reinterpret_cast<float4*>(es)[t]       = v0;
    reinterpret_cast<float4*>(es)[t + 256] = v1;
    reinterpret_cast<float4*>(es)[t + 512] = v2;
    reinterpret_cast<float4*>(es)[t + 768] = v3;
    if (ch < 7) {                      // prefetch next chunk during compute
      const int nb = (ch + 1) * 1024 + t;
      v0 = esrc[nb];
      v1 = esrc[nb + 256];
      v2 = esrc[nb + 512];
      v3 = esrc[nb + 768];
    }
    __syncthreads();                   // es ready

    #pragma unroll
    for (int cc = 0; cc < 8; ++cc) {
      const int c = ch * 8 + cc;
      const float4 xa = *reinterpret_cast<const float4*>(&xs[c * 32 + posb]);
      const float4 xbq = *reinterpret_cast<const float4*>(&xs[c * 32 + posb + 4]);
      const float4 e0 = *reinterpret_cast<const float4*>(&es[cc * NE + kb]);
      const float4 e1 = *reinterpret_cast<const float4*>(&es[cc * NE + kb + 4]);
      const float xr[8] = {xa.x, xa.y, xa.z, xa.w, xbq.x, xbq.y, xbq.z, xbq.w};
      const float er[8] = {e0.x, e0.y, e0.z, e0.w, e1.x, e1.y, e1.z, e1.w};
      #pragma unroll
      for (int pi = 0; pi < 8; ++pi)
        #pragma unroll
        for (int j = 0; j < 8; ++j)
          acc[pi][j] = fmaf(xr[pi], er[j], acc[pi][j]);  // c-ascending chain == BLAS order
    }
  }
  __syncthreads();                     // es done; safe to overlay smin/sidx

  // ---- dist + per-lane argmin (acc == -2*cross complete)
  const float4 xq0 = *reinterpret_cast<const float4*>(&xsq[posb]);
  const float4 xq1 = *reinterpret_cast<const float4*>(&xsq[posb + 4]);
  const float xqv[8] = {xq0.x, xq0.y, xq0.z, xq0.w, xq1.x, xq1.y, xq1.z, xq1.w};
  const float4 eq0 = *reinterpret_cast<const float4*>(esq + kb);
  const float4 eq1 = *reinterpret_cast<const float4*>(esq + kb + 4);
  const float esv[8] = {eq0.x, eq0.y, eq0.z, eq0.w, eq1.x, eq1.y, eq1.z, eq1.w};

  float bestd[8];
  int   besti[8];
  #pragma unroll
  for (int pi = 0; pi < 8; ++pi) {
    bestd[pi] = __builtin_inff();
    besti[pi] = 0;
    #pragma unroll
    for (int j = 0; j < 8; ++j) {     // ascending j: first-index-wins
      const float d = (xqv[pi] + esv[j]) + acc[pi][j];  // == (xsq+esq) - 2*cross
      if (d < bestd[pi]) { bestd[pi] = d; besti[pi] = kb + j; }
    }
  }

  // ---- combine: slot s = 16wc+q covers codes [8s,8s+8); ascending-s scan
  const int s = wc * 16 + q;
  *reinterpret_cast<float4*>(&smin[s * 32 + posb]) =
      make_float4(bestd[0], bestd[1], bestd[2], bestd[3]);
  *reinterpret_cast<float4*>(&smin[s * 32 + posb + 4]) =
      make_float4(bestd[4], bestd[5], bestd[6], bestd[7]);
  *reinterpret_cast<int4*>(&sidx[s * 32 + posb]) =
      make_int4(besti[0], besti[1], besti[2], besti[3]);
  *reinterpret_cast<int4*>(&sidx[s * 32 + posb + 4]) =
      make_int4(besti[4], besti[5], besti[6], besti[7]);
  __syncthreads();
  if (t < 32) {
    float bd = smin[t];
    int   bi = sidx[t];
    #pragma unroll
    for (int ss = 1; ss < 64; ++ss) {
      const float d = smin[ss * 32 + t];
      if (d < bd) { bd = d; bi = sidx[ss * 32 + t]; }
    }
    bcomb[t] = bi;
  }
  __syncthreads();

  // ---- gather winning codebook row (L2-hot), coalesced stores
  {
    const int pos = t & 31, cr = t >> 5;
    const int idx = bcomb[pos];
    const float* __restrict__ eq = e + idx * HD;
    #pragma unroll
    for (int i = 0; i < 8; ++i) {
      const int c = cr + 8 * i;
      out[xbase + (size_t)c * HW + pos] = eq[c];
    }
  }
}

extern "C" void kernel_launch(void* const* d_in, const int* in_sizes, int n_in,
                              void* d_out, int out_size, void* d_ws, size_t ws_size,
                              hipStream_t stream) {
  const float* x = (const float*)d_in[0];   // (64, 64, 32, 32) fp32
  const float* e = (const float*)d_in[1];   // (512, 64) fp32
  float* epT = (float*)d_ws;                // 64*512 floats: -2*e transposed
  float* esq = epT + HD * NE;               // 512 floats
  float* out = (float*)d_out;

  vq_prep_kernel<<<130, 256, 0, stream>>>(e, epT, esq);
  vq_main_kernel<<<2048, 256, 0, stream>>>(x, epT, esq, e, out);
}

// Round 10
// 134.434 us; speedup vs baseline: 2.8394x; 2.8394x over previous
//
#include <hip/hip_runtime.h>

#define HD 64       // HIDDEN_DIM
#define NE 512      // N_EMBEDS
#define HW 1024     // 32*32 spatial positions per batch image

// ---------------------------------------------------------------------------
// Prep (130 blocks x 256):
//  blk 0..127 : epT[c][k] = -2 * e[k][c]   (transposed, code-major rows)
//               -2 fold bit-exact (pow2 scale commutes with fp32 rounding).
//  blk 128/129: esq[k] = np.sum(e[k]*e[k]), numpy pairwise-8, no contraction.
//  Verified absmax==0.0 R1-R9.
// ---------------------------------------------------------------------------
__global__ __launch_bounds__(256) void vq_prep_kernel(const float* __restrict__ e,
                                                      float* __restrict__ epT,
                                                      float* __restrict__ esq) {
  const int blk = blockIdx.x;
  if (blk < 128) {
    const int t = blk * 256 + threadIdx.x;     // 0..32767
    const int c = t >> 9, k = t & 511;
    epT[t] = -2.0f * e[k * HD + c];
  } else {
    const int k = (blk - 128) * 256 + threadIdx.x;   // 0..511
    const float4* __restrict__ rowv = reinterpret_cast<const float4*>(e + k * HD);
    float row[HD];
    #pragma unroll
    for (int i = 0; i < 16; ++i) {
      const float4 v = rowv[i];
      row[4 * i + 0] = v.x; row[4 * i + 1] = v.y;
      row[4 * i + 2] = v.z; row[4 * i + 3] = v.w;
    }
    float result;
    {
      #pragma clang fp contract(off)
      float r[8];
      #pragma unroll
      for (int j = 0; j < 8; ++j) r[j] = row[j] * row[j];
      #pragma unroll
      for (int i = 8; i < HD; i += 8) {
        #pragma unroll
        for (int j = 0; j < 8; ++j) r[j] = r[j] + row[i + j] * row[i + j];
      }
      result = ((r[0] + r[1]) + (r[2] + r[3])) + ((r[4] + r[5]) + (r[6] + r[7]));
    }
    esq[k] = result;
  }
}

// ---------------------------------------------------------------------------
// Main R10: 2048 blocks x 256 (4 waves). Block = 32 positions x 512 codes.
//
// R9 post-mortem: launch_bounds min-waves bound does NOT stop the allocator
// targeting 8 waves/EU (VGPR pinned 64 -> acc[8][8] spilled, 1 GB scratch).
// Fix 1: amdgpu_waves_per_eu(4,4) -- min AND max -> allocator budget 128.
// Fix 2: split operand transport: x via LDS (2 ds_read_b128/c), e via
// global dwordx4 from L2-hot epT (no es staging, no chunk barriers).
// Per-CU pipe model: LDS 4096x12 ~ 20 us || VMEM 4096x16 ~ 27 us ||
// VALU FMA ~ 27.3 us -- balanced, vs R8's 68 us all-through-LDS queue.
//
// Geometry: wave = code quarter wc. Lane: p=lane&3 -> positions 8p..8p+7;
// q=lane>>2 -> codes kb=128wc+8q..+7. acc[8][8] persists over c
// (c=0..63 ascending sequential fmaf chain per (pos,code) == BLAS order,
// identical rounding to R3-R9 => absmax 0.0). Slot s=16wc+q covers codes
// [8s,8s+8); ascending-s combine == np.argmin first-index-wins.
// ---------------------------------------------------------------------------
__global__ __launch_bounds__(256)
__attribute__((amdgpu_waves_per_eu(4, 4)))
void vq_main_kernel(const float* __restrict__ x,
                    const float* __restrict__ epT,
                    const float* __restrict__ esq,
                    const float* __restrict__ e,
                    float* __restrict__ out) {
  __shared__ float xs[HD * 32];        // 8 KB  [c][pos]
  __shared__ float smin[64 * 32];      // 8 KB  [slot][pos]
  __shared__ int   sidx[64 * 32];      // 8 KB
  __shared__ float xsq[32];
  __shared__ int   bcomb[32];

  const int t    = threadIdx.x;
  const int lane = t & 63;
  const int wc   = t >> 6;             // 0..3  wave = code quarter
  const int p    = lane & 3;           // pos-octet group
  const int q    = lane >> 2;          // 0..15 code slot
  const int posb = p * 8;              // lane's 8 positions
  const int kb   = wc * 128 + q * 8;   // lane's 8 codes

  const int blk = blockIdx.x;          // 2048
  const int b   = blk >> 5;
  const int s0  = (blk & 31) << 5;
  const size_t xbase = (size_t)b * (HD * HW) + s0;

  // ---- stage x into LDS [c][pos] (256 threads x 8 floats, coalesced)
  {
    const int pos = t & 31, cr = t >> 5;        // cr 0..7
    #pragma unroll
    for (int i = 0; i < 8; ++i) {
      const int c = cr + 8 * i;
      xs[c * 32 + pos] = x[xbase + (size_t)c * HW + pos];
    }
  }
  __syncthreads();

  // ---- xsq[pos]: numpy pairwise-8, no contraction (bit-exact)
  if (t < 32) {
    #pragma clang fp contract(off)
    float r[8];
    #pragma unroll
    for (int j = 0; j < 8; ++j) {
      const float v = xs[j * 32 + t];
      r[j] = v * v;
    }
    #pragma unroll
    for (int i = 8; i < HD; i += 8) {
      #pragma unroll
      for (int j = 0; j < 8; ++j) {
        const float v = xs[(i + j) * 32 + t];
        r[j] = r[j] + v * v;
      }
    }
    xsq[t] = ((r[0] + r[1]) + (r[2] + r[3])) + ((r[4] + r[5]) + (r[6] + r[7]));
  }
  __syncthreads();

  // ---- 8 pos x 8 codes register tile; x from LDS, e from global (L2-hot)
  const float4* __restrict__ ev = reinterpret_cast<const float4*>(epT);
  const int e4 = kb >> 2;              // float4 index within 128-wide row

  float acc[8][8];
  #pragma unroll
  for (int pi = 0; pi < 8; ++pi)
    #pragma unroll
    for (int j = 0; j < 8; ++j) acc[pi][j] = 0.f;

  #pragma unroll 4
  for (int c = 0; c < HD; ++c) {
    const float4 e0 = ev[c * 128 + e4];
    const float4 e1 = ev[c * 128 + e4 + 1];
    const float4 xa = *reinterpret_cast<const float4*>(&xs[c * 32 + posb]);
    const float4 xb = *reinterpret_cast<const float4*>(&xs[c * 32 + posb + 4]);
    const float xr[8] = {xa.x, xa.y, xa.z, xa.w, xb.x, xb.y, xb.z, xb.w};
    const float er[8] = {e0.x, e0.y, e0.z, e0.w, e1.x, e1.y, e1.z, e1.w};
    #pragma unroll
    for (int pi = 0; pi < 8; ++pi)
      #pragma unroll
      for (int j = 0; j < 8; ++j)
        acc[pi][j] = fmaf(xr[pi], er[j], acc[pi][j]);  // c-ascending chain == BLAS order
  }

  // ---- dist + per-lane argmin (acc == -2*cross complete)
  const float4 xq0 = *reinterpret_cast<const float4*>(&xsq[posb]);
  const float4 xq1 = *reinterpret_cast<const float4*>(&xsq[posb + 4]);
  const float xqv[8] = {xq0.x, xq0.y, xq0.z, xq0.w, xq1.x, xq1.y, xq1.z, xq1.w};
  const float4 eq0 = *reinterpret_cast<const float4*>(esq + kb);
  const float4 eq1 = *reinterpret_cast<const float4*>(esq + kb + 4);
  const float esv[8] = {eq0.x, eq0.y, eq0.z, eq0.w, eq1.x, eq1.y, eq1.z, eq1.w};

  float bestd[8];
  int   besti[8];
  #pragma unroll
  for (int pi = 0; pi < 8; ++pi) {
    bestd[pi] = __builtin_inff();
    besti[pi] = 0;
    #pragma unroll
    for (int j = 0; j < 8; ++j) {     // ascending j: first-index-wins
      const float d = (xqv[pi] + esv[j]) + acc[pi][j];  // == (xsq+esq) - 2*cross
      if (d < bestd[pi]) { bestd[pi] = d; besti[pi] = kb + j; }
    }
  }

  // ---- combine: slot s = 16wc+q covers codes [8s,8s+8); ascending-s scan
  const int s = wc * 16 + q;
  *reinterpret_cast<float4*>(&smin[s * 32 + posb]) =
      make_float4(bestd[0], bestd[1], bestd[2], bestd[3]);
  *reinterpret_cast<float4*>(&smin[s * 32 + posb + 4]) =
      make_float4(bestd[4], bestd[5], bestd[6], bestd[7]);
  *reinterpret_cast<int4*>(&sidx[s * 32 + posb]) =
      make_int4(besti[0], besti[1], besti[2], besti[3]);
  *reinterpret_cast<int4*>(&sidx[s * 32 + posb + 4]) =
      make_int4(besti[4], besti[5], besti[6], besti[7]);
  __syncthreads();
  if (t < 32) {
    float bd = smin[t];
    int   bi = sidx[t];
    #pragma unroll
    for (int ss = 1; ss < 64; ++ss) {
      const float d = smin[ss * 32 + t];
      if (d < bd) { bd = d; bi = sidx[ss * 32 + t]; }
    }
    bcomb[t] = bi;
  }
  __syncthreads();

  // ---- gather winning codebook row (L2-hot), coalesced stores
  {
    const int pos = t & 31, cr = t >> 5;
    const int idx = bcomb[pos];
    const float* __restrict__ eq = e + idx * HD;
    #pragma unroll
    for (int i = 0; i < 8; ++i) {
      const int c = cr + 8 * i;
      out[xbase + (size_t)c * HW + pos] = eq[c];
    }
  }
}

extern "C" void kernel_launch(void* const* d_in, const int* in_sizes, int n_in,
                              void* d_out, int out_size, void* d_ws, size_t ws_size,
                              hipStream_t stream) {
  const float* x = (const float*)d_in[0];   // (64, 64, 32, 32) fp32
  const float* e = (const float*)d_in[1];   // (512, 64) fp32
  float* epT = (float*)d_ws;                // 64*512 floats: -2*e transposed
  float* esq = epT + HD * NE;               // 512 floats
  float* out = (float*)d_out;

  vq_prep_kernel<<<130, 256, 0, stream>>>(e, epT, esq);
  vq_main_kernel<<<2048, 256, 0, stream>>>(x, epT, esq, e, out);
}

// Round 11
// 125.147 us; speedup vs baseline: 3.0501x; 1.0742x over previous
//
#include <hip/hip_runtime.h>

#define HD 64       // HIDDEN_DIM
#define NE 512      // N_EMBEDS
#define HW 1024     // 32*32 spatial positions per batch image

typedef float f32x2 __attribute__((ext_vector_type(2)));

// ---------------------------------------------------------------------------
// Prep (130 blocks x 256):
//  blk 0..127 : epT[c][k] = -2 * e[k][c]   (transposed, code-major rows)
//               -2 fold bit-exact (pow2 scale commutes with fp32 rounding).
//  blk 128/129: esq[k] = np.sum(e[k]*e[k]), numpy pairwise-8, no contraction.
//  Verified absmax==0.0 R1-R10.
// ---------------------------------------------------------------------------
__global__ __launch_bounds__(256) void vq_prep_kernel(const float* __restrict__ e,
                                                      float* __restrict__ epT,
                                                      float* __restrict__ esq) {
  const int blk = blockIdx.x;
  if (blk < 128) {
    const int t = blk * 256 + threadIdx.x;     // 0..32767
    const int c = t >> 9, k = t & 511;
    epT[t] = -2.0f * e[k * HD + c];
  } else {
    const int k = (blk - 128) * 256 + threadIdx.x;   // 0..511
    const float4* __restrict__ rowv = reinterpret_cast<const float4*>(e + k * HD);
    float row[HD];
    #pragma unroll
    for (int i = 0; i < 16; ++i) {
      const float4 v = rowv[i];
      row[4 * i + 0] = v.x; row[4 * i + 1] = v.y;
      row[4 * i + 2] = v.z; row[4 * i + 3] = v.w;
    }
    float result;
    {
      #pragma clang fp contract(off)
      float r[8];
      #pragma unroll
      for (int j = 0; j < 8; ++j) r[j] = row[j] * row[j];
      #pragma unroll
      for (int i = 8; i < HD; i += 8) {
        #pragma unroll
        for (int j = 0; j < 8; ++j) r[j] = r[j] + row[i + j] * row[i + j];
      }
      result = ((r[0] + r[1]) + (r[2] + r[3])) + ((r[4] + r[5]) + (r[6] + r[7]));
    }
    esq[k] = result;
  }
}

// ---------------------------------------------------------------------------
// Main R11: 2048 blocks x 256 (4 waves). Block = 32 positions x 512 codes.
//
// R7/R8/R10 all hit a ~70 us transport-pipe wall (whichever pipe carries the
// strided/duplicated operand traffic saturates). R11 cuts both pipes:
//  - e staged to LDS per 8-c chunk via global_load_lds width=16 (coalesced,
//    zero data VGPRs -- removes R9's staging register pressure/spill).
//  - 8 pos x 8 codes lane tile: 4 ds_read_b128 per 64 FMAs -> LDS pipe
//    ~8192 instr/CU x 12 cyc ~ 41 us (vs R8's 68 us at 3-per-32).
//  - v_pk_fma_f32 pairs adjacent POSITIONS (natural from the x-quad);
//    e broadcast via op_sel (no movs). Each half is IEEE fp32 fma with the
//    same sequential-c chain -> bit-exact; FMA issue 27.3 -> 13.7 us.
//
// Geometry: wave = code quarter wc. Lane: p=lane&3 -> positions 8p..8p+7
// (4 pairs); q=lane>>2 -> codes kb=128wc+8q..+7. Slot s=16wc+q covers
// codes [8s,8s+8); ascending-s combine == np.argmin first-index-wins.
// smin/sidx overlay es (exactly 16 KB) after the last compute barrier.
// ---------------------------------------------------------------------------
__global__ __launch_bounds__(256)
__attribute__((amdgpu_waves_per_eu(4, 4)))
void vq_main_kernel(const float* __restrict__ x,
                    const float* __restrict__ epT,
                    const float* __restrict__ esq,
                    const float* __restrict__ e,
                    float* __restrict__ out) {
  __shared__ float xs[HD * 32];        // 8 KB  [c][pos]
  __shared__ float es[8 * NE];         // 16 KB chunk [cc][k]; overlaid later
  __shared__ float xsq[32];
  __shared__ int   bcomb[32];

  float* smin = es;                    // [64 slots][32 pos] floats (8 KB)
  int*   sidx = (int*)(es + 64 * 32);  // [64 slots][32 pos] ints   (8 KB)

  const int t    = threadIdx.x;
  const int lane = t & 63;
  const int wc   = t >> 6;             // 0..3  wave = code quarter
  const int p    = lane & 3;           // pos-octet group
  const int q    = lane >> 2;          // 0..15 code slot
  const int posb = p * 8;              // lane's 8 positions
  const int kb   = wc * 128 + q * 8;   // lane's 8 codes

  const int blk = blockIdx.x;          // 2048
  const int b   = blk >> 5;
  const int s0  = (blk & 31) << 5;
  const size_t xbase = (size_t)b * (HD * HW) + s0;

  // ---- stage x into LDS [c][pos] (256 threads x 8 floats, coalesced)
  {
    const int pos = t & 31, cr = t >> 5;        // cr 0..7
    #pragma unroll
    for (int i = 0; i < 8; ++i) {
      const int c = cr + 8 * i;
      xs[c * 32 + pos] = x[xbase + (size_t)c * HW + pos];
    }
  }
  __syncthreads();

  // ---- xsq[pos]: numpy pairwise-8, no contraction (bit-exact)
  if (t < 32) {
    #pragma clang fp contract(off)
    float r[8];
    #pragma unroll
    for (int j = 0; j < 8; ++j) {
      const float v = xs[j * 32 + t];
      r[j] = v * v;
    }
    #pragma unroll
    for (int i = 8; i < HD; i += 8) {
      #pragma unroll
      for (int j = 0; j < 8; ++j) {
        const float v = xs[(i + j) * 32 + t];
        r[j] = r[j] + v * v;
      }
    }
    xsq[t] = ((r[0] + r[1]) + (r[2] + r[3])) + ((r[4] + r[5]) + (r[6] + r[7]));
  }

  // ---- chunked accumulate: es <- epT chunk via global_load_lds (async DMA)
  float4* es4 = reinterpret_cast<float4*>(es);
  const float4* __restrict__ g4 = reinterpret_cast<const float4*>(epT);

  f32x2 acc2[4][8];                    // [pos-pair][code j]: 64 VGPRs
  #pragma unroll
  for (int pi = 0; pi < 4; ++pi)
    #pragma unroll
    for (int j = 0; j < 8; ++j) acc2[pi][j] = (f32x2)(0.f);

  #pragma unroll 1
  for (int ch = 0; ch < 8; ++ch) {
    __syncthreads();                   // es free (prev chunk consumed / xsq done)
    #pragma unroll
    for (int i = 0; i < 4; ++i) {      // 1024 float4 = 16 KB, lane-contiguous
      __builtin_amdgcn_global_load_lds(
          (const __attribute__((address_space(1))) void*)(g4 + (size_t)ch * 1024 + i * 256 + t),
          (__attribute__((address_space(3))) void*)(es4 + i * 256 + t),
          16, 0, 0);
    }
    __builtin_amdgcn_s_waitcnt(0xF70); // vmcnt(0): own DMA done
    __syncthreads();                   // everyone's DMA done

    #pragma unroll 2
    for (int cc = 0; cc < 8; ++cc) {
      const int c = ch * 8 + cc;
      const float4 xa = *reinterpret_cast<const float4*>(&xs[c * 32 + posb]);
      const float4 xb = *reinterpret_cast<const float4*>(&xs[c * 32 + posb + 4]);
      const float4 e0 = *reinterpret_cast<const float4*>(&es[cc * NE + kb]);
      const float4 e1 = *reinterpret_cast<const float4*>(&es[cc * NE + kb + 4]);
      f32x2 xp[4]; f32x2 ep[4];
      xp[0][0] = xa.x; xp[0][1] = xa.y;  xp[1][0] = xa.z; xp[1][1] = xa.w;
      xp[2][0] = xb.x; xp[2][1] = xb.y;  xp[3][0] = xb.z; xp[3][1] = xb.w;
      ep[0][0] = e0.x; ep[0][1] = e0.y;  ep[1][0] = e0.z; ep[1][1] = e0.w;
      ep[2][0] = e1.x; ep[2][1] = e1.y;  ep[3][0] = e1.z; ep[3][1] = e1.w;
      #pragma unroll
      for (int pi = 0; pi < 4; ++pi) {
        #pragma unroll
        for (int jp = 0; jp < 4; ++jp) {
          // code 2jp  : e-pair LOW dword broadcast to both halves
          asm("v_pk_fma_f32 %0, %1, %2, %0 op_sel:[0,0,0] op_sel_hi:[1,0,1]"
              : "+v"(acc2[pi][2 * jp]) : "v"(xp[pi]), "v"(ep[jp]));
          // code 2jp+1: e-pair HIGH dword broadcast to both halves
          asm("v_pk_fma_f32 %0, %1, %2, %0 op_sel:[0,1,0] op_sel_hi:[1,1,1]"
              : "+v"(acc2[pi][2 * jp + 1]) : "v"(xp[pi]), "v"(ep[jp]));
        }
      }
    }
  }
  __syncthreads();                     // es done; safe to overlay smin/sidx

  // ---- dist + per-lane argmin (acc == -2*cross complete)
  const float4 xq0 = *reinterpret_cast<const float4*>(&xsq[posb]);
  const float4 xq1 = *reinterpret_cast<const float4*>(&xsq[posb + 4]);
  const float xqv[8] = {xq0.x, xq0.y, xq0.z, xq0.w, xq1.x, xq1.y, xq1.z, xq1.w};
  const float4 eq0 = *reinterpret_cast<const float4*>(esq + kb);
  const float4 eq1 = *reinterpret_cast<const float4*>(esq + kb + 4);
  const float esv[8] = {eq0.x, eq0.y, eq0.z, eq0.w, eq1.x, eq1.y, eq1.z, eq1.w};

  float bestd[8];
  int   besti[8];
  #pragma unroll
  for (int pi = 0; pi < 8; ++pi) {
    bestd[pi] = __builtin_inff();
    besti[pi] = 0;
    const int pr = pi >> 1, ph = pi & 1;        // pair index, half
    #pragma unroll
    for (int j = 0; j < 8; ++j) {               // ascending j: first-index-wins
      const float d = (xqv[pi] + esv[j]) + acc2[pr][j][ph];  // == (xsq+esq) - 2*cross
      if (d < bestd[pi]) { bestd[pi] = d; besti[pi] = kb + j; }
    }
  }

  // ---- combine: slot s = 16wc+q covers codes [8s,8s+8); ascending-s scan
  const int s = wc * 16 + q;
  *reinterpret_cast<float4*>(&smin[s * 32 + posb]) =
      make_float4(bestd[0], bestd[1], bestd[2], bestd[3]);
  *reinterpret_cast<float4*>(&smin[s * 32 + posb + 4]) =
      make_float4(bestd[4], bestd[5], bestd[6], bestd[7]);
  *reinterpret_cast<int4*>(&sidx[s * 32 + posb]) =
      make_int4(besti[0], besti[1], besti[2], besti[3]);
  *reinterpret_cast<int4*>(&sidx[s * 32 + posb + 4]) =
      make_int4(besti[4], besti[5], besti[6], besti[7]);
  __syncthreads();
  if (t < 32) {
    float bd = smin[t];
    int   bi = sidx[t];
    #pragma unroll
    for (int ss = 1; ss < 64; ++ss) {
      const float d = smin[ss * 32 + t];
      if (d < bd) { bd = d; bi = sidx[ss * 32 + t]; }
    }
    bcomb[t] = bi;
  }
  __syncthreads();

  // ---- gather winning codebook row (L2-hot), coalesced stores
  {
    const int pos = t & 31, cr = t >> 5;
    const int idx = bcomb[pos];
    const float* __restrict__ eq = e + idx * HD;
    #pragma unroll
    for (int i = 0; i < 8; ++i) {
      const int c = cr + 8 * i;
      out[xbase + (size_t)c * HW + pos] = eq[c];
    }
  }
}

extern "C" void kernel_launch(void* const* d_in, const int* in_sizes, int n_in,
                              void* d_out, int out_size, void* d_ws, size_t ws_size,
                              hipStream_t stream) {
  const float* x = (const float*)d_in[0];   // (64, 64, 32, 32) fp32
  const float* e = (const float*)d_in[1];   // (512, 64) fp32
  float* epT = (float*)d_ws;                // 64*512 floats: -2*e transposed
  float* esq = epT + HD * NE;               // 512 floats
  float* out = (float*)d_out;

  vq_prep_kernel<<<130, 256, 0, stream>>>(e, epT, esq);
  vq_main_kernel<<<2048, 256, 0, stream>>>(x, epT, esq, e, out);
}